// Round 11
// baseline (245.574 us; speedup 1.0000x reference)
//
#include <hip/hip_runtime.h>
#include <stdint.h>

#define NN 8192       // nodes
#define WPR 256       // u32 words per bitmask row (8192 bits)
#define CSTRIDE 192   // CSR slots/row; P[deg>192] ~ 1e-40 for Poisson(64); writes guarded

typedef _Float16 f16;
typedef f16 f16x2 __attribute__((ext_vector_type(2)));
typedef f16 f16x4 __attribute__((ext_vector_type(4)));
typedef f16 f16x8 __attribute__((ext_vector_type(8)));
typedef float f32x4 __attribute__((ext_vector_type(4)));

// ---------------------------------------------------------------------------
// Adjacency bitmask: set semantics (duplicates collapse) via atomicOr
// ---------------------------------------------------------------------------
__global__ __launch_bounds__(256) void build_adj(const int* __restrict__ ei,
                                                 uint32_t* __restrict__ mask,
                                                 int E) {
  int t = blockIdx.x * blockDim.x + threadIdx.x;
  if (t >= E) return;
  int a = ei[t];        // e0
  int b = ei[E + t];    // e1
  atomicOr(&mask[(size_t)a * WPR + (b >> 5)], 1u << (b & 31));
  atomicOr(&mask[(size_t)b * WPR + (a >> 5)], 1u << (a & 31));
}

// ---------------------------------------------------------------------------
// Bitmask -> fixed-stride CSR (uint16 ids) + dinv. One wave per row. Self-edge
// bit stays (diag=2 case); eye handled separately in spmm. dinv=rsqrt(pop+1).
// ---------------------------------------------------------------------------
__global__ __launch_bounds__(256) void mask_to_csr(const uint32_t* __restrict__ mask,
                                                   uint16_t* __restrict__ cols,
                                                   int* __restrict__ nnz,
                                                   float* __restrict__ dinv) {
  const int row = blockIdx.x * 4 + (threadIdx.x >> 6);
  const int lane = threadIdx.x & 63;
  const uint4 w = ((const uint4*)(mask + (size_t)row * WPR))[lane];
  const int c = __popc(w.x) + __popc(w.y) + __popc(w.z) + __popc(w.w);
  int inc = c;
#pragma unroll
  for (int o = 1; o < 64; o <<= 1) {
    int v = __shfl_up(inc, o);
    if (lane >= o) inc += v;
  }
  const int total = __shfl(inc, 63);
  int base = row * CSTRIDE + (inc - c);
  const int lim = row * CSTRIDE + CSTRIDE;
  uint32_t ws_[4] = {w.x, w.y, w.z, w.w};
#pragma unroll
  for (int i = 0; i < 4; ++i) {
    uint32_t word = ws_[i];
    int boff = (lane * 4 + i) << 5;
    while (word) {
      int b = __ffs(word) - 1;
      word &= word - 1;
      if (base < lim) cols[base] = (uint16_t)(boff + b);
      ++base;
    }
  }
  if (lane == 0) {
    nnz[row] = (total > CSTRIDE) ? CSTRIDE : total;
    dinv[row] = rsqrtf((float)(total + 1));
  }
}

// ---------------------------------------------------------------------------
// One-shot prep:
//  blocks 0..639   : W fp32 [K][N] -> Wt f16 [N][K] (32x32 LDS transpose)
//  blocks 640..2687: x fp32 -> Xh f16 straight copy (8 elems/thread)
// ---------------------------------------------------------------------------
__global__ __launch_bounds__(256) void prep_all(const float* __restrict__ W1,
                                                const float* __restrict__ W2,
                                                const float* __restrict__ W3,
                                                const float* __restrict__ x,
                                                f16* __restrict__ T1,
                                                f16* __restrict__ T2,
                                                f16* __restrict__ T3,
                                                f16* __restrict__ Xh) {
  int tile = blockIdx.x;
  if (tile >= 640) {  // x convert: 2048 elems per block
    size_t base = (size_t)(tile - 640) * 2048 + threadIdx.x * 8;
    float4 v0 = *(const float4*)&x[base];
    float4 v1 = *(const float4*)&x[base + 4];
    f16x8 h = {(f16)v0.x, (f16)v0.y, (f16)v0.z, (f16)v0.w,
               (f16)v1.x, (f16)v1.y, (f16)v1.z, (f16)v1.w};
    *(f16x8*)&Xh[base] = h;
    return;
  }
  const float* W; f16* T; int N;
  if (tile < 256)      { W = W1; T = T1; N = 512; }
  else if (tile < 512) { W = W2; T = T2; N = 512; tile -= 256; }
  else                 { W = W3; T = T3; N = 256; tile -= 512; }
  const int K = 512;
  const int ntn = N >> 5;
  const int k0 = (tile / ntn) << 5, n0 = (tile % ntn) << 5;
  __shared__ f16 tl[32][33];
  const int tx = threadIdx.x & 31, ty = threadIdx.x >> 5;
#pragma unroll
  for (int r = 0; r < 32; r += 8)
    tl[ty + r][tx] = (f16)W[(size_t)(k0 + ty + r) * N + n0 + tx];
  __syncthreads();
#pragma unroll
  for (int r = 0; r < 32; r += 8)
    T[(size_t)(n0 + ty + r) * K + k0 + tx] = tl[tx][ty + r];
}

// ---------------------------------------------------------------------------
// f16-MFMA GEMM: Ys[m,:] = (f16)( rs[m] * (A@Wt^T)[m,:] )
// A f16 [M,K] row-major; Wt f16 [N][K] (pre-transposed).
// BM=128, BN=64, BK=32; 256 thr = 2x2 waves; 16x16x32 f16 MFMA.
// A frag: row=lane&15, k=(lane>>4)*8+j. B frag: col=lane&15, same k.
// D frag: row=(lane>>4)*4+r, col=lane&15 (m89-verified, dtype-independent).
// ---------------------------------------------------------------------------
__global__ __launch_bounds__(256) void gemm_f16(const f16* __restrict__ A,
                                                const f16* __restrict__ Wt,
                                                const float* __restrict__ rs,
                                                f16* __restrict__ Ys,
                                                int M, int N, int K) {
  __shared__ f16 As[128][40];  // [m][k], pad -> benign 2-way conflicts
  __shared__ f16 Bs[64][40];   // [n][k]
  const int t = threadIdx.x;
  const int lane = t & 63;
  const int w = t >> 6;
  const int wr = w >> 1, wc = w & 1;          // 2x2 wave grid
  const int m0 = blockIdx.y * 128, n0 = blockIdx.x * 64;
  const int lm = lane & 15, kg = lane >> 4;   // fragment row/col, k-group
  const int k0f = kg * 8;

  f32x4 acc[4][2] = {};

  for (int k0 = 0; k0 < K; k0 += 32) {
    // stage A: 128x32 f16, 2 f16x8 per thread.
#pragma unroll
    for (int l = 0; l < 2; ++l) {
      int idx = l * 256 + t;
      int row = idx >> 2;
      int c8 = (idx & 3) * 8;
      f16x8 h = *(const f16x8*)&A[(size_t)(m0 + row) * K + k0 + c8];
      *(f16x8*)&As[row][c8] = h;
    }
    // stage Wt: 64 n x 32 k f16, one f16x8 vector copy per thread.
    {
      int n = t >> 2, k8 = (t & 3) * 8;
      *(f16x8*)&Bs[n][k8] = *(const f16x8*)&Wt[(size_t)(n0 + n) * K + k0 + k8];
    }
    __syncthreads();

    f16x8 af[4], bf[2];
#pragma unroll
    for (int mf = 0; mf < 4; ++mf)
      af[mf] = *(const f16x8*)&As[wr * 64 + mf * 16 + lm][k0f];
#pragma unroll
    for (int nf = 0; nf < 2; ++nf)
      bf[nf] = *(const f16x8*)&Bs[wc * 32 + nf * 16 + lm][k0f];
#pragma unroll
    for (int mf = 0; mf < 4; ++mf)
#pragma unroll
      for (int nf = 0; nf < 2; ++nf)
        acc[mf][nf] = __builtin_amdgcn_mfma_f32_16x16x32_f16(af[mf], bf[nf], acc[mf][nf], 0, 0, 0);
    __syncthreads();
  }

  // epilogue: row-scale by rs, convert f16, store
#pragma unroll
  for (int mf = 0; mf < 4; ++mf) {
#pragma unroll
    for (int r = 0; r < 4; ++r) {
      int row = m0 + wr * 64 + mf * 16 + kg * 4 + r;
      float s = rs[row];
#pragma unroll
      for (int nf = 0; nf < 2; ++nf) {
        int col = n0 + wc * 32 + nf * 16 + lm;
        Ys[(size_t)row * N + col] = (f16)(s * acc[mf][nf][r]);
      }
    }
  }
}

// ---------------------------------------------------------------------------
// Column-chunked CSR SpMM, v3: 128-col chunks (2 MB << 4 MB XCD L2 — the
// Round-9 regression showed 4 MB chunks thrash). Wave split by NEIGHBOR
// PARITY: lanes 0-31 even neighbors, 32-63 odd; each half covers the full
// 128-col chunk at f16x4/lane -> per 2 neighbors: 1 ds_read + 1 addr add +
// 1 dwordx2 load + 2 pk_add (~40% fewer issue slots than f16x2).
// Cross-half combine via shfl_xor(32); tail+eye after combine on all lanes
// (halves identical then); half 0 writes.
// ---------------------------------------------------------------------------
template <int NC, typename OutT, bool RELU>
__global__ __launch_bounds__(256) void spmm_csr(const uint16_t* __restrict__ cols,
                                                const int* __restrict__ nnz,
                                                const float* __restrict__ dinv,
                                                const f16* __restrict__ Ys,
                                                const float* __restrict__ bias,
                                                OutT* __restrict__ out) {
  constexpr int Q = NC / 128;       // 2 MB chunks
  constexpr uint32_t RB = NC * 2;   // row bytes
  const int b = blockIdx.x;
  const int chunk = b % Q;          // stable per-XCD under round-robin dispatch
  const int rg = b / Q;
  const int w = threadIdx.x >> 6, lane = threadIdx.x & 63;
  const int half = lane >> 5;       // neighbor parity class
  const int li = lane & 31;
  const int row = rg * 4 + w;
  const int cb = chunk * 128 + li * 4;   // same cols for lane and lane^32

  __shared__ uint32_t coff[4][CSTRIDE];
  const int n = nnz[row];
  for (int k = lane; k < n; k += 64)
    coff[w][k] = (uint32_t)cols[row * CSTRIDE + k] * RB;
  __syncthreads();

  const char* __restrict__ Yb = (const char*)(Ys + cb);
  float a0 = 0.f, a1 = 0.f, a2 = 0.f, a3 = 0.f;
  int k = 0;
  for (; k + 8 <= n; k += 8) {     // 4 pairs; this half handles k+2p+half
    f16x4 v0 = *(const f16x4*)(Yb + coff[w][k + 0 + half]);
    f16x4 v1 = *(const f16x4*)(Yb + coff[w][k + 2 + half]);
    f16x4 v2 = *(const f16x4*)(Yb + coff[w][k + 4 + half]);
    f16x4 v3 = *(const f16x4*)(Yb + coff[w][k + 6 + half]);
    f16x4 s = (v0 + v1) + (v2 + v3);   // 3 f16x4 pk-adds
    a0 += (float)s[0]; a1 += (float)s[1]; a2 += (float)s[2]; a3 += (float)s[3];
  }
  for (; k + 2 <= n; k += 2) {
    f16x4 v = *(const f16x4*)(Yb + coff[w][k + half]);
    a0 += (float)v[0]; a1 += (float)v[1]; a2 += (float)v[2]; a3 += (float)v[3];
  }
  // cross-half combine: both halves then hold the full partial sum
  a0 += __shfl_xor(a0, 32);
  a1 += __shfl_xor(a1, 32);
  a2 += __shfl_xor(a2, 32);
  a3 += __shfl_xor(a3, 32);
  if (k < n) {  // odd tail neighbor, once on all lanes (halves stay identical)
    f16x4 v = *(const f16x4*)(Yb + coff[w][k]);
    a0 += (float)v[0]; a1 += (float)v[1]; a2 += (float)v[2]; a3 += (float)v[3];
  }
  {
    f16x4 vs = *(const f16x4*)(Yb + (uint32_t)row * RB);  // +I (eye)
    a0 += (float)vs[0]; a1 += (float)vs[1]; a2 += (float)vs[2]; a3 += (float)vs[3];
  }
  if (half == 0) {
    const float di = dinv[row];
    float4 bv = *(const float4*)&bias[cb];
    float o0 = di * a0 + bv.x;
    float o1 = di * a1 + bv.y;
    float o2 = di * a2 + bv.z;
    float o3 = di * a3 + bv.w;
    if (RELU) {
      o0 = fmaxf(o0, 0.f); o1 = fmaxf(o1, 0.f);
      o2 = fmaxf(o2, 0.f); o3 = fmaxf(o3, 0.f);
    }
    if constexpr (sizeof(OutT) == 4) {
      *(float4*)&out[(size_t)row * NC + cb] = make_float4(o0, o1, o2, o3);
    } else {
      f16x4 h = {(f16)o0, (f16)o1, (f16)o2, (f16)o3};
      *(f16x4*)&out[(size_t)row * NC + cb] = h;
    }
  }
}

// ---------------------------------------------------------------------------
extern "C" void kernel_launch(void* const* d_in, const int* in_sizes, int n_in,
                              void* d_out, int out_size, void* d_ws, size_t ws_size,
                              hipStream_t stream) {
  const float* x  = (const float*)d_in[0];
  const int*   ei = (const int*)d_in[1];
  const float* W1 = (const float*)d_in[2];
  const float* b1 = (const float*)d_in[3];
  const float* W2 = (const float*)d_in[4];
  const float* b2 = (const float*)d_in[5];
  const float* W3 = (const float*)d_in[6];
  const float* b3 = (const float*)d_in[7];
  float* out = (float*)d_out;
  const int E = in_sizes[1] / 2;

  // Workspace (~29 MB). mask aliases Ys: mask dead after mask_to_csr, before
  // gemm1's first write to Ys.
  uint8_t* ws = (uint8_t*)d_ws;
  size_t off = 0;
  uint16_t* cols = (uint16_t*)ws;            off += (size_t)CSTRIDE * NN * 2;  // 3 MB
  int*      nnz  = (int*)(ws + off);         off += (size_t)NN * 4;            // 32 KB
  float*    dinv = (float*)(ws + off);       off += (size_t)NN * 4;            // 32 KB
  f16*      Wt1  = (f16*)(ws + off);         off += (size_t)512 * 512 * 2;     // 512 KB
  f16*      Wt2  = (f16*)(ws + off);         off += (size_t)512 * 512 * 2;     // 512 KB
  f16*      Wt3  = (f16*)(ws + off);         off += (size_t)256 * 512 * 2;     // 256 KB
  f16*      Xh   = (f16*)(ws + off);         off += (size_t)NN * 512 * 2;      // 8 MB
  f16*      H    = (f16*)(ws + off);         off += (size_t)NN * 512 * 2;      // 8 MB
  f16*      Ys   = (f16*)(ws + off);                                           // 8 MB
  uint32_t* mask = (uint32_t*)Ys;                                              // alias

  // ws is poisoned 0xAA before every call -> rebuild adjacency every launch
  hipMemsetAsync(mask, 0, (size_t)NN * WPR * sizeof(uint32_t), stream);
  build_adj<<<(E + 255) / 256, 256, 0, stream>>>(ei, mask, E);
  mask_to_csr<<<NN / 4, 256, 0, stream>>>(mask, cols, nnz, dinv);
  prep_all<<<2688, 256, 0, stream>>>(W1, W2, W3, x, Wt1, Wt2, Wt3, Xh);

  // Layer 1: Ys = f16(dinv ⊙ (Xh@W1)); H = relu(dinv ⊙ ((A+I)·Ys) + b1) in f16
  gemm_f16<<<dim3(8, 64), 256, 0, stream>>>(Xh, Wt1, dinv, Ys, NN, 512, 512);
  spmm_csr<512, f16, true><<<(NN / 4) * 4, 256, 0, stream>>>(cols, nnz, dinv, Ys, b1, H);

  // Layer 2
  gemm_f16<<<dim3(8, 64), 256, 0, stream>>>(H, Wt2, dinv, Ys, NN, 512, 512);
  spmm_csr<512, f16, true><<<(NN / 4) * 4, 256, 0, stream>>>(cols, nnz, dinv, Ys, b2, H);

  // Layer 3 (no ReLU), fp32 -> d_out
  gemm_f16<<<dim3(4, 64), 256, 0, stream>>>(H, Wt3, dinv, Ys, NN, 256, 512);
  spmm_csr<256, float, false><<<(NN / 4) * 2, 256, 0, stream>>>(cols, nnz, dinv, Ys, b3, out);
}

// Round 12
// 223.182 us; speedup vs baseline: 1.1003x; 1.1003x over previous
//
#include <hip/hip_runtime.h>
#include <stdint.h>

#define NN 8192       // nodes
#define WPR 256       // u32 words per bitmask row (8192 bits)
#define CSTRIDE 192   // CSR slots/row; P[deg>192] ~ 1e-40 for Poisson(64); writes guarded

typedef _Float16 f16;
typedef f16 f16x2 __attribute__((ext_vector_type(2)));
typedef f16 f16x4 __attribute__((ext_vector_type(4)));
typedef f16 f16x8 __attribute__((ext_vector_type(8)));
typedef float f32x4 __attribute__((ext_vector_type(4)));

// ---------------------------------------------------------------------------
// Adjacency bitmask: set semantics (duplicates collapse) via atomicOr
// ---------------------------------------------------------------------------
__global__ __launch_bounds__(256) void build_adj(const int* __restrict__ ei,
                                                 uint32_t* __restrict__ mask,
                                                 int E) {
  int t = blockIdx.x * blockDim.x + threadIdx.x;
  if (t >= E) return;
  int a = ei[t];        // e0
  int b = ei[E + t];    // e1
  atomicOr(&mask[(size_t)a * WPR + (b >> 5)], 1u << (b & 31));
  atomicOr(&mask[(size_t)b * WPR + (a >> 5)], 1u << (a & 31));
}

// ---------------------------------------------------------------------------
// Bitmask -> fixed-stride CSR (uint16 ids) + dinv. One wave per row. Self-edge
// bit stays (diag=2 case); eye handled separately in spmm. dinv=rsqrt(pop+1).
// ---------------------------------------------------------------------------
__global__ __launch_bounds__(256) void mask_to_csr(const uint32_t* __restrict__ mask,
                                                   uint16_t* __restrict__ cols,
                                                   int* __restrict__ nnz,
                                                   float* __restrict__ dinv) {
  const int row = blockIdx.x * 4 + (threadIdx.x >> 6);
  const int lane = threadIdx.x & 63;
  const uint4 w = ((const uint4*)(mask + (size_t)row * WPR))[lane];
  const int c = __popc(w.x) + __popc(w.y) + __popc(w.z) + __popc(w.w);
  int inc = c;
#pragma unroll
  for (int o = 1; o < 64; o <<= 1) {
    int v = __shfl_up(inc, o);
    if (lane >= o) inc += v;
  }
  const int total = __shfl(inc, 63);
  int base = row * CSTRIDE + (inc - c);
  const int lim = row * CSTRIDE + CSTRIDE;
  uint32_t ws_[4] = {w.x, w.y, w.z, w.w};
#pragma unroll
  for (int i = 0; i < 4; ++i) {
    uint32_t word = ws_[i];
    int boff = (lane * 4 + i) << 5;
    while (word) {
      int b = __ffs(word) - 1;
      word &= word - 1;
      if (base < lim) cols[base] = (uint16_t)(boff + b);
      ++base;
    }
  }
  if (lane == 0) {
    nnz[row] = (total > CSTRIDE) ? CSTRIDE : total;
    dinv[row] = rsqrtf((float)(total + 1));
  }
}

// ---------------------------------------------------------------------------
// One-shot weight prep: W fp32 [K=512][N] -> Wt f16 [N][K] (transposed),
// so GEMM B-staging is a pure f16x8 vector copy. Blocks 0..255 -> W1,
// 256..511 -> W2, 512..639 -> W3. 32x32 LDS tile transpose.
// ---------------------------------------------------------------------------
__global__ __launch_bounds__(256) void wcvt_all(const float* __restrict__ W1,
                                                const float* __restrict__ W2,
                                                const float* __restrict__ W3,
                                                f16* __restrict__ T1,
                                                f16* __restrict__ T2,
                                                f16* __restrict__ T3) {
  int tile = blockIdx.x;
  const float* W; f16* T; int N;
  if (tile < 256)      { W = W1; T = T1; N = 512; }
  else if (tile < 512) { W = W2; T = T2; N = 512; tile -= 256; }
  else                 { W = W3; T = T3; N = 256; tile -= 512; }
  const int K = 512;
  const int ntn = N >> 5;
  const int k0 = (tile / ntn) << 5, n0 = (tile % ntn) << 5;
  __shared__ f16 tl[32][33];
  const int tx = threadIdx.x & 31, ty = threadIdx.x >> 5;
#pragma unroll
  for (int r = 0; r < 32; r += 8)
    tl[ty + r][tx] = (f16)W[(size_t)(k0 + ty + r) * N + n0 + tx];
  __syncthreads();
#pragma unroll
  for (int r = 0; r < 32; r += 8)
    T[(size_t)(n0 + ty + r) * K + k0 + tx] = tl[tx][ty + r];
}

// ---------------------------------------------------------------------------
// f16-MFMA GEMM: Ys[m,:] = (f16)( rs[m] * (A@Wt^T)[m,:] )
// A [M,K] row-major (fp32 or f16); Wt f16 [N][K] (pre-transposed).
// BM=128, BN=64, BK=32; 256 thr = 2x2 waves; 16x16x32 f16 MFMA.
// A frag: row=lane&15, k=(lane>>4)*8+j. B frag: col=lane&15, same k.
// D frag: row=(lane>>4)*4+r, col=lane&15 (m89-verified, dtype-independent).
// ---------------------------------------------------------------------------
template <typename AT>
__global__ __launch_bounds__(256) void gemm_f16(const AT* __restrict__ A,
                                                const f16* __restrict__ Wt,
                                                const float* __restrict__ rs,
                                                f16* __restrict__ Ys,
                                                int M, int N, int K) {
  __shared__ f16 As[128][40];  // [m][k], pad -> benign 2-way conflicts
  __shared__ f16 Bs[64][40];   // [n][k]
  const int t = threadIdx.x;
  const int lane = t & 63;
  const int w = t >> 6;
  const int wr = w >> 1, wc = w & 1;          // 2x2 wave grid
  const int m0 = blockIdx.y * 128, n0 = blockIdx.x * 64;
  const int lm = lane & 15, kg = lane >> 4;   // fragment row/col, k-group
  const int k0f = kg * 8;

  f32x4 acc[4][2] = {};

  for (int k0 = 0; k0 < K; k0 += 32) {
    if constexpr (sizeof(AT) == 4) {
      // stage A: 128x32 fp32 -> f16. 4 float4 per thread.
#pragma unroll
      for (int l = 0; l < 4; ++l) {
        int row = (t >> 3) + l * 32;
        int c4 = (t & 7) * 4;
        float4 v = *(const float4*)&A[(size_t)(m0 + row) * K + k0 + c4];
        f16x4 h = {(f16)v.x, (f16)v.y, (f16)v.z, (f16)v.w};
        *(f16x4*)&As[row][c4] = h;
      }
    } else {
      // stage A: 128x32 f16 direct. 2 f16x8 per thread.
#pragma unroll
      for (int l = 0; l < 2; ++l) {
        int idx = l * 256 + t;
        int row = idx >> 2;
        int c8 = (idx & 3) * 8;
        f16x8 h = *(const f16x8*)&A[(size_t)(m0 + row) * K + k0 + c8];
        *(f16x8*)&As[row][c8] = h;
      }
    }
    // stage Wt: 64 n x 32 k f16, one f16x8 vector copy per thread.
    {
      int n = t >> 2, k8 = (t & 3) * 8;
      *(f16x8*)&Bs[n][k8] = *(const f16x8*)&Wt[(size_t)(n0 + n) * K + k0 + k8];
    }
    __syncthreads();

    f16x8 af[4], bf[2];
#pragma unroll
    for (int mf = 0; mf < 4; ++mf)
      af[mf] = *(const f16x8*)&As[wr * 64 + mf * 16 + lm][k0f];
#pragma unroll
    for (int nf = 0; nf < 2; ++nf)
      bf[nf] = *(const f16x8*)&Bs[wc * 32 + nf * 16 + lm][k0f];
#pragma unroll
    for (int mf = 0; mf < 4; ++mf)
#pragma unroll
      for (int nf = 0; nf < 2; ++nf)
        acc[mf][nf] = __builtin_amdgcn_mfma_f32_16x16x32_f16(af[mf], bf[nf], acc[mf][nf], 0, 0, 0);
    __syncthreads();
  }

  // epilogue: row-scale by rs, convert f16, store
#pragma unroll
  for (int mf = 0; mf < 4; ++mf) {
#pragma unroll
    for (int r = 0; r < 4; ++r) {
      int row = m0 + wr * 64 + mf * 16 + kg * 4 + r;
      float s = rs[row];
#pragma unroll
      for (int nf = 0; nf < 2; ++nf) {
        int col = n0 + wc * 32 + nf * 16 + lm;
        Ys[(size_t)row * N + col] = (f16)(s * acc[mf][nf][r]);
      }
    }
  }
}

// ---------------------------------------------------------------------------
// Column-chunked CSR SpMM (proven R6 structure, MLP deepened 8->16).
//   out[row, chunk] = dinv[row]*( sum_j Ys[j, chunk] + Ys[row, chunk] ) + bias
// chunk = blockIdx % Q (Q = NC/128, 2 MB chunks): under round-robin block->XCD
// dispatch each XCD touches one chunk -> L2-resident gathers. Block = 4 rows;
// one wave per row; lane covers 2 cols (f16x2). Inner loop: 16 INDEPENDENT
// dword gathers in flight per wave (latency/MLP-bound regime per R9/R10
// post-mortem), packed f16x2 tree-sum, fp32 flush per 16.
// ---------------------------------------------------------------------------
template <int NC, typename OutT, bool RELU>
__global__ __launch_bounds__(256) void spmm_csr(const uint16_t* __restrict__ cols,
                                                const int* __restrict__ nnz,
                                                const float* __restrict__ dinv,
                                                const f16* __restrict__ Ys,
                                                const float* __restrict__ bias,
                                                OutT* __restrict__ out) {
  constexpr int Q = NC / 128;
  const int b = blockIdx.x;
  const int chunk = b % Q;          // == XCD%Q under round-robin dispatch
  const int rg = b / Q;
  const int w = threadIdx.x >> 6, lane = threadIdx.x & 63;
  const int row = rg * 4 + w;
  const int cb = chunk * 128 + 2 * lane;

  __shared__ uint16_t cidx[4][CSTRIDE];
  const int n = nnz[row];
  for (int k = lane; k < n; k += 64) cidx[w][k] = cols[row * CSTRIDE + k];
  __syncthreads();

  const f16* __restrict__ Yc = Ys + cb;
  float a0 = 0.f, a1 = 0.f;
  int k = 0;
  for (; k + 16 <= n; k += 16) {   // 16 independent loads in flight
    f16x2 v0  = *(const f16x2*)&Yc[(size_t)cidx[w][k + 0]  * NC];
    f16x2 v1  = *(const f16x2*)&Yc[(size_t)cidx[w][k + 1]  * NC];
    f16x2 v2  = *(const f16x2*)&Yc[(size_t)cidx[w][k + 2]  * NC];
    f16x2 v3  = *(const f16x2*)&Yc[(size_t)cidx[w][k + 3]  * NC];
    f16x2 v4  = *(const f16x2*)&Yc[(size_t)cidx[w][k + 4]  * NC];
    f16x2 v5  = *(const f16x2*)&Yc[(size_t)cidx[w][k + 5]  * NC];
    f16x2 v6  = *(const f16x2*)&Yc[(size_t)cidx[w][k + 6]  * NC];
    f16x2 v7  = *(const f16x2*)&Yc[(size_t)cidx[w][k + 7]  * NC];
    f16x2 v8  = *(const f16x2*)&Yc[(size_t)cidx[w][k + 8]  * NC];
    f16x2 v9  = *(const f16x2*)&Yc[(size_t)cidx[w][k + 9]  * NC];
    f16x2 v10 = *(const f16x2*)&Yc[(size_t)cidx[w][k + 10] * NC];
    f16x2 v11 = *(const f16x2*)&Yc[(size_t)cidx[w][k + 11] * NC];
    f16x2 v12 = *(const f16x2*)&Yc[(size_t)cidx[w][k + 12] * NC];
    f16x2 v13 = *(const f16x2*)&Yc[(size_t)cidx[w][k + 13] * NC];
    f16x2 v14 = *(const f16x2*)&Yc[(size_t)cidx[w][k + 14] * NC];
    f16x2 v15 = *(const f16x2*)&Yc[(size_t)cidx[w][k + 15] * NC];
    f16x2 s0 = ((v0 + v1) + (v2 + v3)) + ((v4 + v5) + (v6 + v7));
    f16x2 s1 = ((v8 + v9) + (v10 + v11)) + ((v12 + v13) + (v14 + v15));
    a0 += (float)s0[0] + (float)s1[0];
    a1 += (float)s0[1] + (float)s1[1];
  }
  for (; k + 8 <= n; k += 8) {
    f16x2 v0 = *(const f16x2*)&Yc[(size_t)cidx[w][k + 0] * NC];
    f16x2 v1 = *(const f16x2*)&Yc[(size_t)cidx[w][k + 1] * NC];
    f16x2 v2 = *(const f16x2*)&Yc[(size_t)cidx[w][k + 2] * NC];
    f16x2 v3 = *(const f16x2*)&Yc[(size_t)cidx[w][k + 3] * NC];
    f16x2 v4 = *(const f16x2*)&Yc[(size_t)cidx[w][k + 4] * NC];
    f16x2 v5 = *(const f16x2*)&Yc[(size_t)cidx[w][k + 5] * NC];
    f16x2 v6 = *(const f16x2*)&Yc[(size_t)cidx[w][k + 6] * NC];
    f16x2 v7 = *(const f16x2*)&Yc[(size_t)cidx[w][k + 7] * NC];
    f16x2 s = ((v0 + v1) + (v2 + v3)) + ((v4 + v5) + (v6 + v7));
    a0 += (float)s[0];
    a1 += (float)s[1];
  }
  for (; k < n; ++k) {
    f16x2 v = *(const f16x2*)&Yc[(size_t)cidx[w][k] * NC];
    a0 += (float)v[0]; a1 += (float)v[1];
  }
  f16x2 vs = *(const f16x2*)&Yc[(size_t)row * NC];  // +I (eye)
  a0 += (float)vs[0]; a1 += (float)vs[1];
  const float di = dinv[row];
  float o0 = di * a0 + bias[cb];
  float o1 = di * a1 + bias[cb + 1];
  if (RELU) { o0 = fmaxf(o0, 0.f); o1 = fmaxf(o1, 0.f); }
  if constexpr (sizeof(OutT) == 4) {
    *(float2*)&out[(size_t)row * NC + cb] = make_float2(o0, o1);
  } else {
    f16x2 h = {(f16)o0, (f16)o1};
    *(f16x2*)&out[(size_t)row * NC + cb] = h;
  }
}

// ---------------------------------------------------------------------------
extern "C" void kernel_launch(void* const* d_in, const int* in_sizes, int n_in,
                              void* d_out, int out_size, void* d_ws, size_t ws_size,
                              hipStream_t stream) {
  const float* x  = (const float*)d_in[0];
  const int*   ei = (const int*)d_in[1];
  const float* W1 = (const float*)d_in[2];
  const float* b1 = (const float*)d_in[3];
  const float* W2 = (const float*)d_in[4];
  const float* b2 = (const float*)d_in[5];
  const float* W3 = (const float*)d_in[6];
  const float* b3 = (const float*)d_in[7];
  float* out = (float*)d_out;
  const int E = in_sizes[1] / 2;

  // Workspace (~21 MB). mask aliases Ys: mask dead after mask_to_csr, before
  // gemm1's first write to Ys.
  uint8_t* ws = (uint8_t*)d_ws;
  size_t off = 0;
  uint16_t* cols = (uint16_t*)ws;            off += (size_t)CSTRIDE * NN * 2;  // 3 MB
  int*      nnz  = (int*)(ws + off);         off += (size_t)NN * 4;            // 32 KB
  float*    dinv = (float*)(ws + off);       off += (size_t)NN * 4;            // 32 KB
  f16*      Wt1  = (f16*)(ws + off);         off += (size_t)512 * 512 * 2;     // 512 KB
  f16*      Wt2  = (f16*)(ws + off);         off += (size_t)512 * 512 * 2;     // 512 KB
  f16*      Wt3  = (f16*)(ws + off);         off += (size_t)256 * 512 * 2;     // 256 KB
  f16*      H    = (f16*)(ws + off);         off += (size_t)NN * 512 * 2;      // 8 MB
  f16*      Ys   = (f16*)(ws + off);                                           // 8 MB
  uint32_t* mask = (uint32_t*)Ys;                                              // alias

  // ws is poisoned 0xAA before every call -> rebuild adjacency every launch
  hipMemsetAsync(mask, 0, (size_t)NN * WPR * sizeof(uint32_t), stream);
  build_adj<<<(E + 255) / 256, 256, 0, stream>>>(ei, mask, E);
  mask_to_csr<<<NN / 4, 256, 0, stream>>>(mask, cols, nnz, dinv);
  wcvt_all<<<640, 256, 0, stream>>>(W1, W2, W3, Wt1, Wt2, Wt3);

  // Layer 1: Ys = f16(dinv ⊙ (x@W1)); H = relu(dinv ⊙ ((A+I)·Ys) + b1) in f16
  gemm_f16<float><<<dim3(8, 64), 256, 0, stream>>>(x, Wt1, dinv, Ys, NN, 512, 512);
  spmm_csr<512, f16, true><<<(NN / 4) * 4, 256, 0, stream>>>(cols, nnz, dinv, Ys, b1, H);

  // Layer 2
  gemm_f16<f16><<<dim3(8, 64), 256, 0, stream>>>(H, Wt2, dinv, Ys, NN, 512, 512);
  spmm_csr<512, f16, true><<<(NN / 4) * 4, 256, 0, stream>>>(cols, nnz, dinv, Ys, b2, H);

  // Layer 3 (no ReLU), fp32 -> d_out
  gemm_f16<f16><<<dim3(4, 64), 256, 0, stream>>>(H, Wt3, dinv, Ys, NN, 256, 512);
  spmm_csr<256, float, false><<<(NN / 4) * 2, 256, 0, stream>>>(cols, nnz, dinv, Ys, b3, out);
}